// Round 4
// baseline (297.301 us; speedup 1.0000x reference)
//
#include <hip/hip_runtime.h>
#include <stdint.h>

// RNN: B=1024, T=200, D_in=300, D_h=256, D_out=2
// prep:   Wx / Whh -> bf16 MFMA fragment order (same layout serves A-operand).
// phase1: U' = (x @ Wx + bh)^T via SWAPPED mfma(Wx^T-frag, x^T-frag): lane
//         holds 4 consecutive outcols -> packed 8B stores; layout matches
//         phase2's per-lane U read exactly.
// phase2: 64 blocks x 16 batch rows, 4 waves x 4 col-tiles. Swapped mfma;
//         h in LDS stride 272 ushorts; packed ds_write_b64; Whh frags
//         resident; U prefetched 2 steps ahead; 1 barrier/step.
// NOTE: v_cvt_pk_bf16_f32 removed (suspected hi/lo operand-order mismatch
//       caused round-3 absmax 0.707) — pack2/f2bf (RNE, proven) everywhere.

typedef short s16x8 __attribute__((ext_vector_type(8)));
typedef float f32x4 __attribute__((ext_vector_type(4)));

__device__ __forceinline__ unsigned short f2bf(float f){
  uint32_t u = __builtin_bit_cast(uint32_t, f);
  u += 0x7fffu + ((u >> 16) & 1u);           // RNE
  return (unsigned short)(u >> 16);
}
__device__ __forceinline__ float bf2f(unsigned short s){
  uint32_t u = ((uint32_t)s) << 16;
  return __builtin_bit_cast(float, u);
}
__device__ __forceinline__ uint32_t pack2(float a, float b){
  return (uint32_t)f2bf(a) | ((uint32_t)f2bf(b) << 16);   // a -> low ushort
}

// ---------------- prep: weight conversion to fragment order ----------------
// wxf layout:  [CT=0..15][ki=0..9][lane=0..63][j=0..7]  (K padded 300->320)
// whhf layout: [CT=0..15][ki=0..7][lane=0..63][j=0..7]
// value = W[k = ki*32 + (lane>>4)*8 + j][col = CT*16 + (lane&15)]
__global__ void prep_kernel(const float* __restrict__ Wh,
                            unsigned short* __restrict__ wxf,
                            unsigned short* __restrict__ whhf){
  int id = blockIdx.x * 256 + threadIdx.x;
  if (id < 81920){
    int j = id & 7, lane = (id >> 3) & 63, rem = id >> 9;
    int ki = rem % 10, CT = rem / 10;
    int k = ki * 32 + ((lane >> 4) << 3) + j;
    int col = CT * 16 + (lane & 15);
    wxf[id] = (k < 300) ? f2bf(Wh[k * 256 + col]) : (unsigned short)0;
  } else if (id < 81920 + 65536){
    int id2 = id - 81920;
    int j = id2 & 7, lane = (id2 >> 3) & 63, rem = id2 >> 9;
    int ki = rem & 7, CT = rem >> 3;
    int k = ki * 32 + ((lane >> 4) << 3) + j;
    int col = CT * 16 + (lane & 15);
    whhf[id2] = f2bf(Wh[(300 + k) * 256 + col]);
  }
}

// ---------------- phase 1: U' = (x @ Wx + bh)^T ----------------
// grid: 1600 blocks = 64 batch-tiles x 25 t-groups; 512 threads (8 waves).
// U storage per (bt,t): 4096 ushorts; value (batch n, outcol CT*16+kg*4+r)
// at offset (CT>>2)*1024 + (kg*16+n)*16 + (CT&3)*4 + r.
__global__ __launch_bounds__(512, 4) void phase1_kernel(
    const float* __restrict__ x, const float* __restrict__ bh,
    const unsigned short* __restrict__ wxf, unsigned short* __restrict__ U){
  __shared__ unsigned short hx[128 * 320];   // 80 KB
  int blk = blockIdx.x;
  int bt = blk / 25;
  int t0 = (blk - bt * 25) * 8;
  int tid = threadIdx.x;
  int w = tid >> 6, l = tid & 63;
  int m = l & 15, kg = l >> 4;

  // ---- stage 16 chunks of 2400 contiguous floats -> bf16 LDS ----
  const float4* xb = (const float4*)x + (long)(bt * 16) * 15000 + t0 * 75;
  for (int i = tid; i < 9600; i += 512){
    int bl = i / 600;
    int j  = i - bl * 600;
    float4 v = xb[(long)bl * 15000 + j];
    int tt = j / 75;
    int k4 = j - tt * 75;
    int idx = (((tt * 16 + bl) * 320) + k4 * 4) ^ ((bl & 7) << 3);
    *(uint2*)(&hx[idx]) = make_uint2(pack2(v.x, v.y), pack2(v.z, v.w));
  }
  for (int i = tid; i < 640; i += 512){
    int r = i / 5, q = i - r * 5;
    int idx = (r * 320 + 300 + q * 4) ^ ((r & 7) << 3);
    *(uint2*)(&hx[idx]) = make_uint2(0u, 0u);
  }

  // ---- weights (A-operand) -> registers; tiles T0=2w, T1=2w+1 ----
  s16x8 Bf0[10], Bf1[10];
  const unsigned short* w0p = wxf + (2 * w + 0) * 5120 + l * 8;
  const unsigned short* w1p = wxf + (2 * w + 1) * 5120 + l * 8;
#pragma unroll
  for (int ki = 0; ki < 10; ki++){
    Bf0[ki] = *(const s16x8*)(w0p + ki * 512);
    Bf1[ki] = *(const s16x8*)(w1p + ki * 512);
  }
  // bias per tile: outcol = T*16 + kg*4 + r
  float4 bv0 = *(const float4*)(bh + (2 * w + 0) * 16 + kg * 4);
  float4 bv1 = *(const float4*)(bh + (2 * w + 1) * 16 + kg * 4);
  __syncthreads();

  int abase = m * 320 + kg * 8;
  int swz = (m & 7) << 3;
#pragma unroll 1
  for (int tt = 0; tt < 8; tt++){
    f32x4 acc0 = {bv0.x, bv0.y, bv0.z, bv0.w};
    f32x4 acc1 = {bv1.x, bv1.y, bv1.z, bv1.w};
    int ab = tt * 5120 + abase;
#pragma unroll
    for (int ki = 0; ki < 10; ki++){
      s16x8 a = *(const s16x8*)(&hx[(ab + ki * 32) ^ swz]);
      acc0 = __builtin_amdgcn_mfma_f32_16x16x32_bf16(Bf0[ki], a, acc0, 0, 0, 0);
      acc1 = __builtin_amdgcn_mfma_f32_16x16x32_bf16(Bf1[ki], a, acc1, 0, 0, 0);
    }
    long base = (long)(bt * 200 + t0 + tt) * 4096;
    uint2 s0 = make_uint2(pack2(acc0[0], acc0[1]), pack2(acc0[2], acc0[3]));
    uint2 s1 = make_uint2(pack2(acc1[0], acc1[1]), pack2(acc1[2], acc1[3]));
    int o0 = (w >> 1) * 1024 + l * 16 + ((w & 1) * 2 + 0) * 4;
    int o1 = (w >> 1) * 1024 + l * 16 + ((w & 1) * 2 + 1) * 4;
    *(uint2*)(U + base + o0) = s0;
    *(uint2*)(U + base + o1) = s1;
  }
}

// ---------------- phase 2: serial recurrence ----------------
// grid: 64 blocks (16 batch rows), 256 threads (4 waves x 4 col-tiles).
__global__ __launch_bounds__(256, 1) void phase2_kernel(
    const unsigned short* __restrict__ U, const unsigned short* __restrict__ whhf,
    const float* __restrict__ Wo, const float* __restrict__ bo,
    float* __restrict__ out){
  __shared__ unsigned short h2[2][16 * 272];  // stride 272 ushorts = 544 B
  __shared__ float flds[16][272];
  int bt = blockIdx.x;
  int tid = threadIdx.x;
  int w = tid >> 6, l = tid & 63;
  int n = l & 15, kg = l >> 4;

  // Whh A-fragments -> registers (4 tiles x 8 ki = 128 VGPR)
  s16x8 Bf[4][8];
#pragma unroll
  for (int tt = 0; tt < 4; tt++)
#pragma unroll
    for (int ki = 0; ki < 8; ki++)
      Bf[tt][ki] = *(const s16x8*)(whhf + ((4 * w + tt) * 8 + ki) * 512 + l * 8);

  for (int i = tid; i < 16 * 272; i += 256) h2[0][i] = 0;  // h0 = 0

  const unsigned short* ub = U + (long)bt * 819200 + w * 1024 + l * 16;
  s16x8 u0c = *(const s16x8*)(ub);           // t=0, tiles 4w+0,4w+1
  s16x8 u1c = *(const s16x8*)(ub + 8);       // t=0, tiles 4w+2,4w+3
  s16x8 u0n = *(const s16x8*)(ub + 4096);
  s16x8 u1n = *(const s16x8*)(ub + 4096 + 8);
  __syncthreads();

  float hv[16];
  int p = 0;
  for (int t = 0; t < 200; t++){
    int tf = (t < 198) ? t + 2 : 199;
    s16x8 u0f = *(const s16x8*)(ub + (long)tf * 4096);
    s16x8 u1f = *(const s16x8*)(ub + (long)tf * 4096 + 8);

    s16x8 a[8];
#pragma unroll
    for (int ki = 0; ki < 8; ki++)
      a[ki] = *(const s16x8*)(&h2[p][n * 272 + ki * 32 + kg * 8]);

    f32x4 acc[4];
#pragma unroll
    for (int r = 0; r < 4; r++){
      acc[0][r] = bf2f((unsigned short)u0c[r]);
      acc[1][r] = bf2f((unsigned short)u0c[4 + r]);
      acc[2][r] = bf2f((unsigned short)u1c[r]);
      acc[3][r] = bf2f((unsigned short)u1c[4 + r]);
    }
#pragma unroll
    for (int ki = 0; ki < 8; ki++){
#pragma unroll
      for (int tt = 0; tt < 4; tt++)
        acc[tt] = __builtin_amdgcn_mfma_f32_16x16x32_bf16(Bf[tt][ki], a[ki], acc[tt], 0, 0, 0);
    }
#pragma unroll
    for (int i = 0; i < 16; i++){
      float c = fminf(fmaxf(acc[i >> 2][i & 3], -4.f), 4.f);
      float e = __expf(2.f * c);
      hv[i] = 1.f - 2.f * __builtin_amdgcn_rcpf(e + 1.f);
    }
#pragma unroll
    for (int tt = 0; tt < 4; tt++){
      uint2 d = make_uint2(pack2(hv[tt * 4], hv[tt * 4 + 1]),
                           pack2(hv[tt * 4 + 2], hv[tt * 4 + 3]));
      *(uint2*)(&h2[p ^ 1][n * 272 + (4 * w + tt) * 16 + kg * 4]) = d;
    }
    __syncthreads();
    p ^= 1;
    u0c = u0n; u1c = u1n; u0n = u0f; u1n = u1f;
  }

  // -------- output head: pre_out = clip(h @ Wo + bo), log_softmax --------
#pragma unroll
  for (int i = 0; i < 16; i++)
    flds[n][(4 * w + (i >> 2)) * 16 + kg * 4 + (i & 3)] = hv[i];
  __syncthreads();
  int row = tid >> 4, q = tid & 15;
  float p0 = 0.f, p1 = 0.f;
#pragma unroll
  for (int jj = 0; jj < 16; jj++){
    float hvv = flds[row][q + 16 * jj];
    p0 += hvv * Wo[(q + 16 * jj) * 2 + 0];
    p1 += hvv * Wo[(q + 16 * jj) * 2 + 1];
  }
#pragma unroll
  for (int mm = 8; mm >= 1; mm >>= 1){
    p0 += __shfl_xor(p0, mm, 16);
    p1 += __shfl_xor(p1, mm, 16);
  }
  if (q == 0){
    p0 = fminf(fmaxf(p0 + bo[0], -4.f), 4.f);
    p1 = fminf(fmaxf(p1 + bo[1], -4.f), 4.f);
    float mx = fmaxf(p0, p1);
    float lse = mx + logf(__expf(p0 - mx) + __expf(p1 - mx));
    int orow = bt * 16 + row;
    out[orow * 2 + 0] = p0 - lse;
    out[orow * 2 + 1] = p1 - lse;
  }
}

extern "C" void kernel_launch(void* const* d_in, const int* in_sizes, int n_in,
                              void* d_out, int out_size, void* d_ws, size_t ws_size,
                              hipStream_t stream){
  const float* x  = (const float*)d_in[0];
  const float* Wh = (const float*)d_in[1];
  const float* bh = (const float*)d_in[2];
  const float* Wo = (const float*)d_in[3];
  const float* bo = (const float*)d_in[4];
  float* out = (float*)d_out;

  unsigned short* U    = (unsigned short*)d_ws;                               // 104857600 B
  unsigned short* wxf  = (unsigned short*)((char*)d_ws + 104857600);          // 163840 B
  unsigned short* whhf = (unsigned short*)((char*)d_ws + 104857600 + 163840); // 131072 B

  prep_kernel<<<576, 256, 0, stream>>>(Wh, wxf, whhf);
  phase1_kernel<<<1600, 512, 0, stream>>>(x, bh, wxf, U);
  phase2_kernel<<<64, 256, 0, stream>>>(U, whhf, Wo, bo, out);
}

// Round 5
// 244.041 us; speedup vs baseline: 1.2182x; 1.2182x over previous
//
#include <hip/hip_runtime.h>
#include <stdint.h>

// RNN: B=1024, T=200, D_in=300, D_h=256, D_out=2
// prep:   Wx / Whh -> bf16 MFMA fragment order (serves swapped A-operand).
// phase1: U' = (x @ Wx + bh)^T via swapped mfma(Wfrag, xfrag). Lane stores
//         ONE uint4 (tiles 2w,2w+1 x r=0..3) at w*512+l*8 -> wave writes
//         1KB contiguous; identical address read back by phase2.
// phase2: 64 blocks x 16 batch rows, 8 waves x 2 col-tiles (2 waves/SIMD).
//         Whh frags pinned in VGPRs via asm; split depth-4 MFMA chains;
//         packed ds_write_b64 h-writes; U prefetch 2 steps; 1 barrier/step.

typedef short s16x8 __attribute__((ext_vector_type(8)));
typedef float f32x4 __attribute__((ext_vector_type(4)));

__device__ __forceinline__ unsigned short f2bf(float f){
  uint32_t u = __builtin_bit_cast(uint32_t, f);
  u += 0x7fffu + ((u >> 16) & 1u);           // RNE
  return (unsigned short)(u >> 16);
}
__device__ __forceinline__ float bf2f(unsigned short s){
  uint32_t u = ((uint32_t)s) << 16;
  return __builtin_bit_cast(float, u);
}
__device__ __forceinline__ uint32_t pack2(float a, float b){
  return (uint32_t)f2bf(a) | ((uint32_t)f2bf(b) << 16);   // a -> low ushort
}

// ---------------- prep: weight conversion to fragment order ----------------
// wxf layout:  [CT=0..15][ki=0..9][lane=0..63][j=0..7]  (K padded 300->320)
// whhf layout: [CT=0..15][ki=0..7][lane=0..63][j=0..7]
// value = W[k = ki*32 + (lane>>4)*8 + j][col = CT*16 + (lane&15)]
__global__ void prep_kernel(const float* __restrict__ Wh,
                            unsigned short* __restrict__ wxf,
                            unsigned short* __restrict__ whhf){
  int id = blockIdx.x * 256 + threadIdx.x;
  if (id < 81920){
    int j = id & 7, lane = (id >> 3) & 63, rem = id >> 9;
    int ki = rem % 10, CT = rem / 10;
    int k = ki * 32 + ((lane >> 4) << 3) + j;
    int col = CT * 16 + (lane & 15);
    wxf[id] = (k < 300) ? f2bf(Wh[k * 256 + col]) : (unsigned short)0;
  } else if (id < 81920 + 65536){
    int id2 = id - 81920;
    int j = id2 & 7, lane = (id2 >> 3) & 63, rem = id2 >> 9;
    int ki = rem & 7, CT = rem >> 3;
    int k = ki * 32 + ((lane >> 4) << 3) + j;
    int col = CT * 16 + (lane & 15);
    whhf[id2] = f2bf(Wh[(300 + k) * 256 + col]);
  }
}

// ---------------- phase 1: U' = (x @ Wx + bh)^T ----------------
// grid: 1600 blocks = 64 batch-tiles x 25 t-groups; 512 threads (8 waves).
// U element (tile T=2w+c, reg r, batch n, kg) at ushort offset
// (bt*200+t)*4096 + w*512 + (kg*16+n)*8 + c*4 + r.
__global__ __launch_bounds__(512, 4) void phase1_kernel(
    const float* __restrict__ x, const float* __restrict__ bh,
    const unsigned short* __restrict__ wxf, unsigned short* __restrict__ U){
  __shared__ unsigned short hx[128 * 320];   // 80 KB
  int blk = blockIdx.x;
  int bt = blk / 25;
  int t0 = (blk - bt * 25) * 8;
  int tid = threadIdx.x;
  int w = tid >> 6, l = tid & 63;
  int m = l & 15, kg = l >> 4;

  // ---- stage 16 chunks of 2400 contiguous floats -> bf16 LDS ----
  const float4* xb = (const float4*)x + (long)(bt * 16) * 15000 + t0 * 75;
  for (int i = tid; i < 9600; i += 512){
    int bl = i / 600;
    int j  = i - bl * 600;
    float4 v = xb[(long)bl * 15000 + j];
    int tt = j / 75;
    int k4 = j - tt * 75;
    int idx = (((tt * 16 + bl) * 320) + k4 * 4) ^ ((bl & 7) << 3);
    *(uint2*)(&hx[idx]) = make_uint2(pack2(v.x, v.y), pack2(v.z, v.w));
  }
  for (int i = tid; i < 640; i += 512){
    int r = i / 5, q = i - r * 5;
    int idx = (r * 320 + 300 + q * 4) ^ ((r & 7) << 3);
    *(uint2*)(&hx[idx]) = make_uint2(0u, 0u);
  }

  // ---- weights (A-operand) -> registers; tiles 2w, 2w+1 ----
  s16x8 Bf0[10], Bf1[10];
  const unsigned short* w0p = wxf + (2 * w + 0) * 5120 + l * 8;
  const unsigned short* w1p = wxf + (2 * w + 1) * 5120 + l * 8;
#pragma unroll
  for (int ki = 0; ki < 10; ki++){
    Bf0[ki] = *(const s16x8*)(w0p + ki * 512);
    Bf1[ki] = *(const s16x8*)(w1p + ki * 512);
  }
  // bias per tile: outcol = T*16 + kg*4 + r
  float4 bv0 = *(const float4*)(bh + (2 * w + 0) * 16 + kg * 4);
  float4 bv1 = *(const float4*)(bh + (2 * w + 1) * 16 + kg * 4);
  __syncthreads();

  int abase = m * 320 + kg * 8;
  int swz = (m & 7) << 3;
#pragma unroll 1
  for (int tt = 0; tt < 8; tt++){
    f32x4 acc0 = {bv0.x, bv0.y, bv0.z, bv0.w};
    f32x4 acc1 = {bv1.x, bv1.y, bv1.z, bv1.w};
    int ab = tt * 5120 + abase;
#pragma unroll
    for (int ki = 0; ki < 10; ki++){
      s16x8 a = *(const s16x8*)(&hx[(ab + ki * 32) ^ swz]);
      acc0 = __builtin_amdgcn_mfma_f32_16x16x32_bf16(Bf0[ki], a, acc0, 0, 0, 0);
      acc1 = __builtin_amdgcn_mfma_f32_16x16x32_bf16(Bf1[ki], a, acc1, 0, 0, 0);
    }
    long base = (long)(bt * 200 + t0 + tt) * 4096;
    uint4 s;
    s.x = pack2(acc0[0], acc0[1]);
    s.y = pack2(acc0[2], acc0[3]);
    s.z = pack2(acc1[0], acc1[1]);
    s.w = pack2(acc1[2], acc1[3]);
    *(uint4*)(U + base + w * 512 + l * 8) = s;   // wave: 1KB contiguous
  }
}

// ---------------- phase 2: serial recurrence ----------------
// grid: 64 blocks (16 batch rows), 512 threads (8 waves x 2 col-tiles).
__global__ __launch_bounds__(512, 2) void phase2_kernel(
    const unsigned short* __restrict__ U, const unsigned short* __restrict__ whhf,
    const float* __restrict__ Wo, const float* __restrict__ bo,
    float* __restrict__ out){
  __shared__ unsigned short h2[2][16 * 272];  // stride 272 ushorts = 544 B
  __shared__ float flds[16][272];
  int bt = blockIdx.x;
  int tid = threadIdx.x;
  int w = tid >> 6, l = tid & 63;
  int n = l & 15, kg = l >> 4;

  // Whh A-fragments (tiles 2w, 2w+1) -> registers, pinned (64 VGPR)
  s16x8 Bf0[8], Bf1[8];
#pragma unroll
  for (int ki = 0; ki < 8; ki++){
    Bf0[ki] = *(const s16x8*)(whhf + ((2 * w + 0) * 8 + ki) * 512 + l * 8);
    Bf1[ki] = *(const s16x8*)(whhf + ((2 * w + 1) * 8 + ki) * 512 + l * 8);
  }
#pragma unroll
  for (int ki = 0; ki < 8; ki++){
    asm volatile("" : "+v"(Bf0[ki]));
    asm volatile("" : "+v"(Bf1[ki]));
  }

  for (int i = tid; i < 16 * 272; i += 512) h2[0][i] = 0;  // h0 = 0

  const unsigned short* ub = U + (long)bt * 819200 + w * 512 + l * 8;
  s16x8 uc = *(const s16x8*)(ub);            // t = 0
  s16x8 un = *(const s16x8*)(ub + 4096);     // t = 1
  __syncthreads();

  float hv[8];
  int p = 0;
  for (int t = 0; t < 200; t++){
    int tf = (t < 198) ? t + 2 : 199;
    s16x8 uf = *(const s16x8*)(ub + (long)tf * 4096);

    s16x8 a[8];
#pragma unroll
    for (int ki = 0; ki < 8; ki++)
      a[ki] = *(const s16x8*)(&h2[p][n * 272 + ki * 32 + kg * 8]);

    f32x4 acc0a, acc1a;
    f32x4 acc0b = {0.f, 0.f, 0.f, 0.f}, acc1b = {0.f, 0.f, 0.f, 0.f};
#pragma unroll
    for (int r = 0; r < 4; r++){
      acc0a[r] = bf2f((unsigned short)uc[r]);
      acc1a[r] = bf2f((unsigned short)uc[4 + r]);
    }
    // split chains: depth 4
#pragma unroll
    for (int ki = 0; ki < 4; ki++){
      acc0a = __builtin_amdgcn_mfma_f32_16x16x32_bf16(Bf0[ki],     a[ki],     acc0a, 0, 0, 0);
      acc1a = __builtin_amdgcn_mfma_f32_16x16x32_bf16(Bf1[ki],     a[ki],     acc1a, 0, 0, 0);
      acc0b = __builtin_amdgcn_mfma_f32_16x16x32_bf16(Bf0[ki + 4], a[ki + 4], acc0b, 0, 0, 0);
      acc1b = __builtin_amdgcn_mfma_f32_16x16x32_bf16(Bf1[ki + 4], a[ki + 4], acc1b, 0, 0, 0);
    }
#pragma unroll
    for (int i = 0; i < 8; i++){
      float pre = (i < 4) ? (acc0a[i] + acc0b[i]) : (acc1a[i - 4] + acc1b[i - 4]);
      float c = fminf(fmaxf(pre, -4.f), 4.f);
      float e = __expf(2.f * c);
      hv[i] = 1.f - 2.f * __builtin_amdgcn_rcpf(e + 1.f);
    }
    // packed h writes: tile T=2w+c, col T*16+kg*4+r
    {
      uint2 d0 = make_uint2(pack2(hv[0], hv[1]), pack2(hv[2], hv[3]));
      uint2 d1 = make_uint2(pack2(hv[4], hv[5]), pack2(hv[6], hv[7]));
      *(uint2*)(&h2[p ^ 1][n * 272 + (2 * w + 0) * 16 + kg * 4]) = d0;
      *(uint2*)(&h2[p ^ 1][n * 272 + (2 * w + 1) * 16 + kg * 4]) = d1;
    }
    __syncthreads();
    p ^= 1;
    uc = un; un = uf;
  }

  // -------- output head: pre_out = clip(h @ Wo + bo), log_softmax --------
#pragma unroll
  for (int i = 0; i < 8; i++){
    int r = i & 3, c = i >> 2;
    flds[n][(2 * w + c) * 16 + kg * 4 + r] = hv[i];
  }
  __syncthreads();
  int row = tid >> 5, q = tid & 31;
  float p0 = 0.f, p1 = 0.f;
#pragma unroll
  for (int jj = 0; jj < 8; jj++){
    float hvv = flds[row][q + 32 * jj];
    p0 += hvv * Wo[(q + 32 * jj) * 2 + 0];
    p1 += hvv * Wo[(q + 32 * jj) * 2 + 1];
  }
#pragma unroll
  for (int mm = 16; mm >= 1; mm >>= 1){
    p0 += __shfl_xor(p0, mm, 32);
    p1 += __shfl_xor(p1, mm, 32);
  }
  if (q == 0){
    p0 = fminf(fmaxf(p0 + bo[0], -4.f), 4.f);
    p1 = fminf(fmaxf(p1 + bo[1], -4.f), 4.f);
    float mx = fmaxf(p0, p1);
    float lse = mx + logf(__expf(p0 - mx) + __expf(p1 - mx));
    int orow = bt * 16 + row;
    out[orow * 2 + 0] = p0 - lse;
    out[orow * 2 + 1] = p1 - lse;
  }
}

extern "C" void kernel_launch(void* const* d_in, const int* in_sizes, int n_in,
                              void* d_out, int out_size, void* d_ws, size_t ws_size,
                              hipStream_t stream){
  const float* x  = (const float*)d_in[0];
  const float* Wh = (const float*)d_in[1];
  const float* bh = (const float*)d_in[2];
  const float* Wo = (const float*)d_in[3];
  const float* bo = (const float*)d_in[4];
  float* out = (float*)d_out;

  unsigned short* U    = (unsigned short*)d_ws;                               // 104857600 B
  unsigned short* wxf  = (unsigned short*)((char*)d_ws + 104857600);          // 163840 B
  unsigned short* whhf = (unsigned short*)((char*)d_ws + 104857600 + 163840); // 131072 B

  prep_kernel<<<576, 256, 0, stream>>>(Wh, wxf, whhf);
  phase1_kernel<<<1600, 512, 0, stream>>>(x, bh, wxf, U);
  phase2_kernel<<<64, 512, 0, stream>>>(U, whhf, Wo, bo, out);
}

// Round 6
// 236.552 us; speedup vs baseline: 1.2568x; 1.0317x over previous
//
#include <hip/hip_runtime.h>
#include <stdint.h>

// RNN: B=1024, T=200, D_in=300, D_h=256, D_out=2
// prep:   Wx / Whh -> bf16 MFMA fragment order (serves swapped A-operand).
// phase1: U' = (x @ Wx + bh)^T via swapped mfma(Wfrag, xfrag). Lane stores
//         ONE uint4 at w*512+l*8 -> wave writes 1KB contiguous; identical
//         address read back by phase2.
// phase2: 64 blocks x 16 batch rows, 8 waves x 2 col-tiles (2 waves/SIMD).
//         Whh frags pinned in VGPRs via per-iteration asm (defeats reload
//         rematerialization: round-5 VGPR=56 proved frags were re-fetched
//         from L2 every step). U prefetch distance 2 via STATIC register
//         rotation (u[4], unroll-by-4, constant slot indices) so the vmcnt
//         wait lands 2 steps (~1300cy) after issue > HBM latency.

typedef short s16x8 __attribute__((ext_vector_type(8)));
typedef float f32x4 __attribute__((ext_vector_type(4)));

__device__ __forceinline__ unsigned short f2bf(float f){
  uint32_t u = __builtin_bit_cast(uint32_t, f);
  u += 0x7fffu + ((u >> 16) & 1u);           // RNE
  return (unsigned short)(u >> 16);
}
__device__ __forceinline__ float bf2f(unsigned short s){
  uint32_t u = ((uint32_t)s) << 16;
  return __builtin_bit_cast(float, u);
}
__device__ __forceinline__ uint32_t pack2(float a, float b){
  return (uint32_t)f2bf(a) | ((uint32_t)f2bf(b) << 16);   // a -> low ushort
}

// ---------------- prep: weight conversion to fragment order ----------------
// wxf layout:  [CT=0..15][ki=0..9][lane=0..63][j=0..7]  (K padded 300->320)
// whhf layout: [CT=0..15][ki=0..7][lane=0..63][j=0..7]
// value = W[k = ki*32 + (lane>>4)*8 + j][col = CT*16 + (lane&15)]
__global__ void prep_kernel(const float* __restrict__ Wh,
                            unsigned short* __restrict__ wxf,
                            unsigned short* __restrict__ whhf){
  int id = blockIdx.x * 256 + threadIdx.x;
  if (id < 81920){
    int j = id & 7, lane = (id >> 3) & 63, rem = id >> 9;
    int ki = rem % 10, CT = rem / 10;
    int k = ki * 32 + ((lane >> 4) << 3) + j;
    int col = CT * 16 + (lane & 15);
    wxf[id] = (k < 300) ? f2bf(Wh[k * 256 + col]) : (unsigned short)0;
  } else if (id < 81920 + 65536){
    int id2 = id - 81920;
    int j = id2 & 7, lane = (id2 >> 3) & 63, rem = id2 >> 9;
    int ki = rem & 7, CT = rem >> 3;
    int k = ki * 32 + ((lane >> 4) << 3) + j;
    int col = CT * 16 + (lane & 15);
    whhf[id2] = f2bf(Wh[(300 + k) * 256 + col]);
  }
}

// ---------------- phase 1: U' = (x @ Wx + bh)^T ----------------
// grid: 1600 blocks = 64 batch-tiles x 25 t-groups; 512 threads (8 waves).
// U element (tile T=2w+c, reg r, batch n, kg) at ushort offset
// (bt*200+t)*4096 + w*512 + (kg*16+n)*8 + c*4 + r.
__global__ __launch_bounds__(512, 4) void phase1_kernel(
    const float* __restrict__ x, const float* __restrict__ bh,
    const unsigned short* __restrict__ wxf, unsigned short* __restrict__ U){
  __shared__ unsigned short hx[128 * 320];   // 80 KB
  int blk = blockIdx.x;
  int bt = blk / 25;
  int t0 = (blk - bt * 25) * 8;
  int tid = threadIdx.x;
  int w = tid >> 6, l = tid & 63;
  int m = l & 15, kg = l >> 4;

  // ---- stage 16 chunks of 2400 contiguous floats -> bf16 LDS ----
  const float4* xb = (const float4*)x + (long)(bt * 16) * 15000 + t0 * 75;
  for (int i = tid; i < 9600; i += 512){
    int bl = i / 600;
    int j  = i - bl * 600;
    float4 v = xb[(long)bl * 15000 + j];
    int tt = j / 75;
    int k4 = j - tt * 75;
    int idx = (((tt * 16 + bl) * 320) + k4 * 4) ^ ((bl & 7) << 3);
    *(uint2*)(&hx[idx]) = make_uint2(pack2(v.x, v.y), pack2(v.z, v.w));
  }
  for (int i = tid; i < 640; i += 512){
    int r = i / 5, q = i - r * 5;
    int idx = (r * 320 + 300 + q * 4) ^ ((r & 7) << 3);
    *(uint2*)(&hx[idx]) = make_uint2(0u, 0u);
  }

  // ---- weights (A-operand) -> registers; tiles 2w, 2w+1 ----
  s16x8 Bf0[10], Bf1[10];
  const unsigned short* w0p = wxf + (2 * w + 0) * 5120 + l * 8;
  const unsigned short* w1p = wxf + (2 * w + 1) * 5120 + l * 8;
#pragma unroll
  for (int ki = 0; ki < 10; ki++){
    Bf0[ki] = *(const s16x8*)(w0p + ki * 512);
    Bf1[ki] = *(const s16x8*)(w1p + ki * 512);
  }
  // bias per tile: outcol = T*16 + kg*4 + r
  float4 bv0 = *(const float4*)(bh + (2 * w + 0) * 16 + kg * 4);
  float4 bv1 = *(const float4*)(bh + (2 * w + 1) * 16 + kg * 4);
  __syncthreads();

  int abase = m * 320 + kg * 8;
  int swz = (m & 7) << 3;
#pragma unroll 1
  for (int tt = 0; tt < 8; tt++){
    f32x4 acc0 = {bv0.x, bv0.y, bv0.z, bv0.w};
    f32x4 acc1 = {bv1.x, bv1.y, bv1.z, bv1.w};
    int ab = tt * 5120 + abase;
#pragma unroll
    for (int ki = 0; ki < 10; ki++){
      s16x8 a = *(const s16x8*)(&hx[(ab + ki * 32) ^ swz]);
      acc0 = __builtin_amdgcn_mfma_f32_16x16x32_bf16(Bf0[ki], a, acc0, 0, 0, 0);
      acc1 = __builtin_amdgcn_mfma_f32_16x16x32_bf16(Bf1[ki], a, acc1, 0, 0, 0);
    }
    long base = (long)(bt * 200 + t0 + tt) * 4096;
    uint4 s;
    s.x = pack2(acc0[0], acc0[1]);
    s.y = pack2(acc0[2], acc0[3]);
    s.z = pack2(acc1[0], acc1[1]);
    s.w = pack2(acc1[2], acc1[3]);
    *(uint4*)(U + base + w * 512 + l * 8) = s;   // wave: 1KB contiguous
  }
}

// ---------------- phase 2: serial recurrence ----------------
// grid: 64 blocks (16 batch rows), 512 threads (8 waves x 2 col-tiles).
__global__ __launch_bounds__(512, 2) void phase2_kernel(
    const unsigned short* __restrict__ U, const unsigned short* __restrict__ whhf,
    const float* __restrict__ Wo, const float* __restrict__ bo,
    float* __restrict__ out){
  __shared__ unsigned short h2[2][16 * 272];  // stride 272 ushorts = 544 B
  __shared__ float flds[16][272];
  int bt = blockIdx.x;
  int tid = threadIdx.x;
  int w = tid >> 6, l = tid & 63;
  int n = l & 15, kg = l >> 4;

  // Whh A-fragments (tiles 2w, 2w+1) -> registers (64 VGPR)
  s16x8 Bf0[8], Bf1[8];
#pragma unroll
  for (int ki = 0; ki < 8; ki++){
    Bf0[ki] = *(const s16x8*)(whhf + ((2 * w + 0) * 8 + ki) * 512 + l * 8);
    Bf1[ki] = *(const s16x8*)(whhf + ((2 * w + 1) * 8 + ki) * 512 + l * 8);
  }

  for (int i = tid; i < 16 * 272; i += 512) h2[0][i] = 0;  // h0 = 0

  const unsigned short* ub = U + (long)bt * 819200 + w * 512 + l * 8;
  s16x8 u[4];
  u[0] = *(const s16x8*)(ub);            // t = 0
  u[1] = *(const s16x8*)(ub + 4096);     // t = 1
  __syncthreads();

  float hv[8];
  int p = 0;
  for (int tq = 0; tq < 50; ++tq){
    // re-pin weight frags every 4 steps: after a volatile "+v" the ONLY
    // legal source of the value is the register -> no reload remat.
#pragma unroll
    for (int ki = 0; ki < 8; ki++){
      asm volatile("" : "+v"(Bf0[ki]), "+v"(Bf1[ki]));
    }
#pragma unroll
    for (int s = 0; s < 4; ++s){
      int t = tq * 4 + s;
      int tf = (t < 198) ? t + 2 : 199;
      u[(s + 2) & 3] = *(const s16x8*)(ub + (long)tf * 4096);  // static slot

      s16x8 a[8];
#pragma unroll
      for (int ki = 0; ki < 8; ki++)
        a[ki] = *(const s16x8*)(&h2[p][n * 272 + ki * 32 + kg * 8]);

      f32x4 acc0a, acc1a;
      f32x4 acc0b = {0.f, 0.f, 0.f, 0.f}, acc1b = {0.f, 0.f, 0.f, 0.f};
#pragma unroll
      for (int r = 0; r < 4; r++){
        acc0a[r] = bf2f((unsigned short)u[s][r]);        // s: compile-time
        acc1a[r] = bf2f((unsigned short)u[s][4 + r]);
      }
      // split chains: depth 4
#pragma unroll
      for (int ki = 0; ki < 4; ki++){
        acc0a = __builtin_amdgcn_mfma_f32_16x16x32_bf16(Bf0[ki],     a[ki],     acc0a, 0, 0, 0);
        acc1a = __builtin_amdgcn_mfma_f32_16x16x32_bf16(Bf1[ki],     a[ki],     acc1a, 0, 0, 0);
        acc0b = __builtin_amdgcn_mfma_f32_16x16x32_bf16(Bf0[ki + 4], a[ki + 4], acc0b, 0, 0, 0);
        acc1b = __builtin_amdgcn_mfma_f32_16x16x32_bf16(Bf1[ki + 4], a[ki + 4], acc1b, 0, 0, 0);
      }
#pragma unroll
      for (int i = 0; i < 8; i++){
        float pre = (i < 4) ? (acc0a[i] + acc0b[i]) : (acc1a[i - 4] + acc1b[i - 4]);
        float c = fminf(fmaxf(pre, -4.f), 4.f);
        float e = __expf(2.f * c);
        hv[i] = 1.f - 2.f * __builtin_amdgcn_rcpf(e + 1.f);
      }
      // packed h writes: tile T=2w+c, col T*16+kg*4+r
      {
        uint2 d0 = make_uint2(pack2(hv[0], hv[1]), pack2(hv[2], hv[3]));
        uint2 d1 = make_uint2(pack2(hv[4], hv[5]), pack2(hv[6], hv[7]));
        *(uint2*)(&h2[p ^ 1][n * 272 + (2 * w + 0) * 16 + kg * 4]) = d0;
        *(uint2*)(&h2[p ^ 1][n * 272 + (2 * w + 1) * 16 + kg * 4]) = d1;
      }
      __syncthreads();
      p ^= 1;
    }
  }

  // -------- output head: pre_out = clip(h @ Wo + bo), log_softmax --------
#pragma unroll
  for (int i = 0; i < 8; i++){
    int r = i & 3, c = i >> 2;
    flds[n][(2 * w + c) * 16 + kg * 4 + r] = hv[i];
  }
  __syncthreads();
  int row = tid >> 5, q = tid & 31;
  float p0 = 0.f, p1 = 0.f;
#pragma unroll
  for (int jj = 0; jj < 8; jj++){
    float hvv = flds[row][q + 32 * jj];
    p0 += hvv * Wo[(q + 32 * jj) * 2 + 0];
    p1 += hvv * Wo[(q + 32 * jj) * 2 + 1];
  }
#pragma unroll
  for (int mm = 16; mm >= 1; mm >>= 1){
    p0 += __shfl_xor(p0, mm, 32);
    p1 += __shfl_xor(p1, mm, 32);
  }
  if (q == 0){
    p0 = fminf(fmaxf(p0 + bo[0], -4.f), 4.f);
    p1 = fminf(fmaxf(p1 + bo[1], -4.f), 4.f);
    float mx = fmaxf(p0, p1);
    float lse = mx + logf(__expf(p0 - mx) + __expf(p1 - mx));
    int orow = bt * 16 + row;
    out[orow * 2 + 0] = p0 - lse;
    out[orow * 2 + 1] = p1 - lse;
  }
}

extern "C" void kernel_launch(void* const* d_in, const int* in_sizes, int n_in,
                              void* d_out, int out_size, void* d_ws, size_t ws_size,
                              hipStream_t stream){
  const float* x  = (const float*)d_in[0];
  const float* Wh = (const float*)d_in[1];
  const float* bh = (const float*)d_in[2];
  const float* Wo = (const float*)d_in[3];
  const float* bo = (const float*)d_in[4];
  float* out = (float*)d_out;

  unsigned short* U    = (unsigned short*)d_ws;                               // 104857600 B
  unsigned short* wxf  = (unsigned short*)((char*)d_ws + 104857600);          // 163840 B
  unsigned short* whhf = (unsigned short*)((char*)d_ws + 104857600 + 163840); // 131072 B

  prep_kernel<<<576, 256, 0, stream>>>(Wh, wxf, whhf);
  phase1_kernel<<<1600, 512, 0, stream>>>(x, bh, wxf, U);
  phase2_kernel<<<64, 512, 0, stream>>>(U, whhf, Wo, bo, out);
}